// Round 2
// 153.583 us; speedup vs baseline: 1.0336x; 1.0336x over previous
//
#include <hip/hip_runtime.h>
#include <stdint.h>

#define NN 256
#define TT 128
#define CC 256
#define TH_F 1.0f
#define EPS_BN_F 1e-5f

#define OUT0_ELEMS (CC * TT * NN)          /* 8388608 */
#define OUT1_OFF   OUT0_ELEMS              /* 8388608 */
#define OUT2_OFF   (OUT0_ELEMS + NN)       /* 8388864 */

#define N0_F4      (OUT0_ELEMS / 4)        /* 2097152 float4 in out0 */
#define NSLICE_F4  (NN * NN / 4)           /* 16384 float4 per t-slice */
#define F4_PER_BLK 1024                    /* 4 float4 per thread */
#define COPY0_BLKS (N0_F4 / F4_PER_BLK)            /* 2048 */
#define COPY2_BLKS (((TT - 1) * NSLICE_F4) / F4_PER_BLK) /* 2032 */

// native vector type — __builtin_nontemporal_* requires a builtin vector,
// not HIP's HIP_vector_type<float,4> class
typedef float vfloat4 __attribute__((ext_vector_type(4)));

// ---------------------------------------------------------------------------
// Kernel 1: blocks 0..255 compute dm (256x256) into out + OUT2_OFF (t=0
// slice). Math kept BIT-IDENTICAL to the verified version: do not re-roll
// the dm<=TH dice. Blocks >=256: out0 = v_rel bulk copy (independent of dm,
// so it overlaps dm compute instead of serializing after it).
// ---------------------------------------------------------------------------
__global__ __launch_bounds__(256) void k1_dm_out0(
        const float* __restrict__ v_rel,
        const float* __restrict__ w1,
        const float* __restrict__ b1,
        const float* __restrict__ bn_g,
        const float* __restrict__ bn_b,
        const float* __restrict__ bn_m,
        const float* __restrict__ bn_v,
        const float* __restrict__ w2,
        const float* __restrict__ b2,
        float* __restrict__ out) {
    const int tid = threadIdx.x;
    if (blockIdx.x < NN) {
        float* __restrict__ dm = out + OUT2_OFF;
        const int m = tid;             // 0..255
        const int n = blockIdx.x;      // 0..255
        const float x0n = v_rel[127 * 256 + n];
        const float x0m = v_rel[127 * 256 + m];
        const float x1n = v_rel[255 * 256 + n];
        const float x1m = v_rel[255 * 256 + m];
        const float d0 = x0n - x0m;
        const float d1 = x1n - x1m;
        float accF = 0.0f, accB = 0.0f;
        #pragma unroll
        for (int o = 0; o < 32; ++o) {
            const float w10 = w1[2 * o], w11 = w1[2 * o + 1];
            const float scale = bn_g[o] / sqrtf(bn_v[o] + EPS_BN_F);
            const float mu = bn_m[o], be = bn_b[o], bb = b1[o], a = w2[o];
            float preF = w10 * d0 + w11 * d1 + bb;
            float preB = w10 * (-d0) + w11 * (-d1) + bb;
            float hF = fmaxf(preF, 0.0f);
            float hB = fmaxf(preB, 0.0f);
            accF += a * ((hF - mu) * scale + be);
            accB += a * ((hB - mu) * scale + be);
        }
        const float sF = expf(accF + b2[0]);
        const float sB = expf(accB + b2[0]);
        dm[n * 256 + m] = 0.5f * (sF + sB);
    } else {
        // out0 = v_rel, 4 float4 per thread, direct index, streaming stores
        const int base = (int)(blockIdx.x - NN) * F4_PER_BLK + tid;
        const vfloat4* __restrict__ in4 = reinterpret_cast<const vfloat4*>(v_rel);
        vfloat4* __restrict__ o0 = reinterpret_cast<vfloat4*>(out);
        #pragma unroll
        for (int q = 0; q < 4; ++q) {
            const int i = base + q * 256;
            __builtin_nontemporal_store(in4[i], o0 + i);
        }
    }
}

__device__ __forceinline__ uint32_t rl32(uint32_t v, uint32_t l) {
    return (uint32_t)__builtin_amdgcn_readlane((int)v, (int)l);
}
__device__ __forceinline__ uint64_t rl64(uint64_t v, uint32_t l) {
    uint32_t lo = rl32((uint32_t)v, l);
    uint32_t hi = rl32((uint32_t)(v >> 32), l);
    return ((uint64_t)hi << 32) | lo;
}

// label of node p (p < 64*NW): lab_g lane (p&63), g = p>>6
template<int NW>
__device__ __forceinline__ uint32_t pick_lab(uint32_t lab0, uint32_t lab1,
                                             uint32_t lab2, uint32_t lab3,
                                             uint32_t p) {
    const uint32_t ls = p & 63u;
    uint32_t a = rl32(lab0, ls);
    if (NW == 1) return a;
    uint32_t b = rl32(lab1, ls);
    const uint32_t g = (p >> 6) & 3u;
    if (NW == 2) return (g & 1u) ? b : a;
    uint32_t c = rl32(lab2, ls);
    uint32_t d = (NW > 3) ? rl32(lab3, ls) : c;
    uint32_t ab = (g & 1u) ? b : a;
    uint32_t cd = (g & 1u) ? d : c;
    return (g & 2u) ? cd : ab;
}

// Rows 64K..64K+63; neighbors c < 64*(K+1) -> only NW=K+1 words matter.
// Lane L holds row (64K+L)'s words in registers; row fetch = readlane.
template<int NW>
__device__ __forceinline__ void scan_chunk(const int K, const int lane,
                                           uint32_t& lab0, uint32_t& lab1,
                                           uint32_t& lab2, uint32_t& lab3,
                                           uint32_t& labw,
                                           const uint64_t* __restrict__ bits) {
    const int base = (K * 64 + lane) * 4;
    uint64_t Wr0 = bits[base + 0];
    uint64_t Wr1 = (NW > 1) ? bits[base + 1] : 0;
    uint64_t Wr2 = (NW > 2) ? bits[base + 2] : 0;
    uint64_t Wr3 = (NW > 3) ? bits[base + 3] : 0;
    for (int rr = 0; rr < 64; ++rr) {
        const uint64_t w0 = rl64(Wr0, (uint32_t)rr);
        const uint64_t w1 = (NW > 1) ? rl64(Wr1, (uint32_t)rr) : 0;
        const uint64_t w2 = (NW > 2) ? rl64(Wr2, (uint32_t)rr) : 0;
        const uint64_t w3 = (NW > 3) ? rl64(Wr3, (uint32_t)rr) : 0;
        // branchless min set-bit over the row (512 = none)
        uint32_t f0 = w0 ? (uint32_t)__builtin_ctzll(w0) : 512u;
        uint32_t p = f0;
        if (NW > 1) { uint32_t f = w1 ? (uint32_t)__builtin_ctzll(w1) + 64u  : 512u; p = p < f ? p : f; }
        if (NW > 2) { uint32_t f = w2 ? (uint32_t)__builtin_ctzll(w2) + 128u : 512u; p = p < f ? p : f; }
        if (NW > 3) { uint32_t f = w3 ? (uint32_t)__builtin_ctzll(w3) + 192u : 512u; p = p < f ? p : f; }
        const uint32_t lc = pick_lab<NW>(lab0, lab1, lab2, lab3, p & 255u);
        // node r (=64K+rr) adopts lc; empty row -> update lane 64 (no lane)
        const uint32_t upd = (p < 256u) ? (uint32_t)rr : 64u;
        labw = ((uint32_t)lane == upd) ? lc : labw;
        uint32_t cur = lc;
        for (;;) {
            const uint64_t Q0 = __ballot(lab0 != cur) & w0;
            const uint64_t Q1 = (NW > 1) ? (__ballot(lab1 != cur) & w1) : 0;
            const uint64_t Q2 = (NW > 2) ? (__ballot(lab2 != cur) & w2) : 0;
            const uint64_t Q3 = (NW > 3) ? (__ballot(lab3 != cur) & w3) : 0;
            if (!(Q0 | Q1 | Q2 | Q3)) break;          // common: fall through
            uint32_t h0 = Q0 ? (uint32_t)__builtin_ctzll(Q0) : 512u;
            uint32_t p2 = h0;
            if (NW > 1) { uint32_t h = Q1 ? (uint32_t)__builtin_ctzll(Q1) + 64u  : 512u; p2 = p2 < h ? p2 : h; }
            if (NW > 2) { uint32_t h = Q2 ? (uint32_t)__builtin_ctzll(Q2) + 128u : 512u; p2 = p2 < h ? p2 : h; }
            if (NW > 3) { uint32_t h = Q3 ? (uint32_t)__builtin_ctzll(Q3) + 192u : 512u; p2 = p2 < h ? p2 : h; }
            const uint32_t lc2 = pick_lab<NW>(lab0, lab1, lab2, lab3, p2);
            lab0 = (lab0 == cur) ? lc2 : lab0;
            if (NW > 1) lab1 = (lab1 == cur) ? lc2 : lab1;
            if (NW > 2) lab2 = (lab2 == cur) ? lc2 : lab2;
            if (NW > 3) lab3 = (lab3 == cur) ? lc2 : lab3;
            cur = lc2;
        }
    }
}

// ---------------------------------------------------------------------------
// Kernel 2. Block 0: build ok-bit matrix in LDS (all 4 waves), then ONLY
// wave 0 runs the register-resident serial scan (the scan is SALU-dominated;
// the CU has one shared scalar pipe, so the previous 4-wave-redundant version
// contended ~4x on scalar issue). Waves 1-3 park at __syncthreads. Wave 0
// publishes labels; ranks with 256 threads. Blocks >=1: out2 broadcast.
// Bit layout: bits[r*4+g] bit q  <=>  ok(r, 64g+q); lab_g lane L = node 64g+L.
// ---------------------------------------------------------------------------
__global__ __launch_bounds__(256) void k2_scan_out2(float* __restrict__ out) {
    const int tid = threadIdx.x;
    const float* __restrict__ dm = out + OUT2_OFF;

    if (blockIdx.x == 0) {
        __shared__ __align__(16) uint64_t bits[1024];
        __shared__ uint32_t lab_arr[256];
        __shared__ uint32_t pres[256];
        __shared__ uint32_t rnk[256];

        // ---- build ok-bit words with all 256 threads ----
        for (int i = 0; i < 4; ++i) {
            const int wid = i * 256 + tid;     // 0..1023
            const int r = wid >> 2;
            const int gw = wid & 3;
            uint64_t bm = 0;
            const int cbase = gw * 64;
            if (cbase < r) {
                const float4* p = reinterpret_cast<const float4*>(dm + r * 256 + cbase);
                #pragma unroll
                for (int q = 0; q < 16; ++q) {
                    const float4 v = p[q];
                    const int c0 = cbase + q * 4;
                    if (c0 + 0 < r && v.x <= TH_F) bm |= 1ull << (q * 4 + 0);
                    if (c0 + 1 < r && v.y <= TH_F) bm |= 1ull << (q * 4 + 1);
                    if (c0 + 2 < r && v.z <= TH_F) bm |= 1ull << (q * 4 + 2);
                    if (c0 + 3 < r && v.w <= TH_F) bm |= 1ull << (q * 4 + 3);
                }
            }
            bits[wid] = bm;
        }
        __syncthreads();

        // ---- serial scan: wave 0 only (identical logic, no scalar-pipe
        //      contention from redundant waves) ----
        if (tid < 64) {
            const int lane = tid;
            uint32_t lab0 = (uint32_t)lane;
            uint32_t lab1 = (uint32_t)(64 + lane);
            uint32_t lab2 = (uint32_t)(128 + lane);
            uint32_t lab3 = (uint32_t)(192 + lane);

            scan_chunk<1>(0, lane, lab0, lab1, lab2, lab3, lab0, bits);
            scan_chunk<2>(1, lane, lab0, lab1, lab2, lab3, lab1, bits);
            scan_chunk<3>(2, lane, lab0, lab1, lab2, lab3, lab2, bits);
            scan_chunk<4>(3, lane, lab0, lab1, lab2, lab3, lab3, bits);

            lab_arr[lane]       = lab0;
            lab_arr[64 + lane]  = lab1;
            lab_arr[128 + lane] = lab2;
            lab_arr[192 + lane] = lab3;
        }
        __syncthreads();

        // ---- ranks: present / cumsum / gather, exactly as reference ----
        pres[tid] = 0;
        __syncthreads();
        pres[lab_arr[tid]] = 1;
        __syncthreads();
        if (tid < 64) {
            const int lane = tid;
            const int c0 = 4 * lane;
            const uint32_t t0 = pres[c0 + 0];
            const uint32_t t1 = pres[c0 + 1];
            const uint32_t t2 = pres[c0 + 2];
            const uint32_t t3 = pres[c0 + 3];
            const uint32_t s0 = t0, s1 = s0 + t1, s2 = s1 + t2, s3 = s2 + t3;
            uint32_t incl = s3;
            #pragma unroll
            for (int off = 1; off < 64; off <<= 1) {
                uint32_t u = __shfl_up(incl, off);
                if (lane >= off) incl += u;
            }
            const uint32_t excl = incl - s3;
            rnk[c0 + 0] = excl + s0 - 1;
            rnk[c0 + 1] = excl + s1 - 1;
            rnk[c0 + 2] = excl + s2 - 1;
            rnk[c0 + 3] = excl + s3 - 1;
        }
        __syncthreads();
        out[OUT1_OFF + tid] = (float)rnk[lab_arr[tid]];
    } else {
        // ---- out2[t] = dm for t = 1..127 (t=0 already holds dm) ----
        const int j = (int)(blockIdx.x - 1) * F4_PER_BLK + tid;
        const vfloat4* __restrict__ dm4 = reinterpret_cast<const vfloat4*>(dm);
        vfloat4* __restrict__ o2 = reinterpret_cast<vfloat4*>(out + OUT2_OFF);
        #pragma unroll
        for (int q = 0; q < 4; ++q) {
            const int jj = j + q * 256;
            __builtin_nontemporal_store(dm4[jj & (NSLICE_F4 - 1)],
                                        o2 + (jj + NSLICE_F4));
        }
    }
}

extern "C" void kernel_launch(void* const* d_in, const int* in_sizes, int n_in,
                              void* d_out, int out_size, void* d_ws, size_t ws_size,
                              hipStream_t stream) {
    const float* v_rel = (const float*)d_in[0];
    const float* w1    = (const float*)d_in[1];
    const float* b1    = (const float*)d_in[2];
    const float* bn_g  = (const float*)d_in[3];
    const float* bn_b  = (const float*)d_in[4];
    const float* bn_m  = (const float*)d_in[5];
    const float* bn_v  = (const float*)d_in[6];
    const float* w2    = (const float*)d_in[7];
    const float* b2    = (const float*)d_in[8];
    float* out = (float*)d_out;

    // K1: dm -> out2 t=0 slice (blocks 0..255) || out0 = v_rel copy
    k1_dm_out0<<<NN + COPY0_BLKS, 256, 0, stream>>>(v_rel, w1, b1, bn_g, bn_b,
                                                    bn_m, bn_v, w2, b2, out);
    // K2: block 0 group scan (wave 0 only) || out2 broadcast
    k2_scan_out2<<<1 + COPY2_BLKS, 256, 0, stream>>>(out);
}

// Round 3
// 117.242 us; speedup vs baseline: 1.3540x; 1.3100x over previous
//
#include <hip/hip_runtime.h>
#include <stdint.h>

#define NN 256
#define TT 128
#define CC 256
#define TH_F 1.0f
#define EPS_BN_F 1e-5f

#define OUT0_ELEMS (CC * TT * NN)          /* 8388608 */
#define OUT1_OFF   OUT0_ELEMS              /* 8388608 */
#define OUT2_OFF   (OUT0_ELEMS + NN)       /* 8388864 */

#define N0_F4      (OUT0_ELEMS / 4)        /* 2097152 float4 in out0 */
#define NSLICE_F4  (NN * NN / 4)           /* 16384 float4 per t-slice */
#define F4_PER_BLK 1024                    /* 4 float4 per thread */
#define COPY0_BLKS (N0_F4 / F4_PER_BLK)            /* 2048 */
#define COPY2_BLKS (((TT - 1) * NSLICE_F4) / F4_PER_BLK) /* 2032 */

// native vector type — __builtin_nontemporal_* requires a builtin vector,
// not HIP's HIP_vector_type<float,4> class
typedef float vfloat4 __attribute__((ext_vector_type(4)));

// ---------------------------------------------------------------------------
// Kernel 1: blocks 0..255 compute dm (256x256) into out + OUT2_OFF (t=0
// slice). Math kept BIT-IDENTICAL to the verified version: do not re-roll
// the dm<=TH dice. Blocks >=256: out0 = v_rel bulk copy.
// ---------------------------------------------------------------------------
__global__ __launch_bounds__(256) void k1_dm_out0(
        const float* __restrict__ v_rel,
        const float* __restrict__ w1,
        const float* __restrict__ b1,
        const float* __restrict__ bn_g,
        const float* __restrict__ bn_b,
        const float* __restrict__ bn_m,
        const float* __restrict__ bn_v,
        const float* __restrict__ w2,
        const float* __restrict__ b2,
        float* __restrict__ out) {
    const int tid = threadIdx.x;
    if (blockIdx.x < NN) {
        float* __restrict__ dm = out + OUT2_OFF;
        const int m = tid;             // 0..255
        const int n = blockIdx.x;      // 0..255
        const float x0n = v_rel[127 * 256 + n];
        const float x0m = v_rel[127 * 256 + m];
        const float x1n = v_rel[255 * 256 + n];
        const float x1m = v_rel[255 * 256 + m];
        const float d0 = x0n - x0m;
        const float d1 = x1n - x1m;
        float accF = 0.0f, accB = 0.0f;
        #pragma unroll
        for (int o = 0; o < 32; ++o) {
            const float w10 = w1[2 * o], w11 = w1[2 * o + 1];
            const float scale = bn_g[o] / sqrtf(bn_v[o] + EPS_BN_F);
            const float mu = bn_m[o], be = bn_b[o], bb = b1[o], a = w2[o];
            float preF = w10 * d0 + w11 * d1 + bb;
            float preB = w10 * (-d0) + w11 * (-d1) + bb;
            float hF = fmaxf(preF, 0.0f);
            float hB = fmaxf(preB, 0.0f);
            accF += a * ((hF - mu) * scale + be);
            accB += a * ((hB - mu) * scale + be);
        }
        const float sF = expf(accF + b2[0]);
        const float sB = expf(accB + b2[0]);
        dm[n * 256 + m] = 0.5f * (sF + sB);
    } else {
        // out0 = v_rel, 4 float4 per thread, direct index, streaming stores
        const int base = (int)(blockIdx.x - NN) * F4_PER_BLK + tid;
        const vfloat4* __restrict__ in4 = reinterpret_cast<const vfloat4*>(v_rel);
        vfloat4* __restrict__ o0 = reinterpret_cast<vfloat4*>(out);
        #pragma unroll
        for (int q = 0; q < 4; ++q) {
            const int i = base + q * 256;
            __builtin_nontemporal_store(in4[i], o0 + i);
        }
    }
}

__device__ __forceinline__ uint32_t rl32(uint32_t v, uint32_t l) {
    return (uint32_t)__builtin_amdgcn_readlane((int)v, (int)l);
}
__device__ __forceinline__ uint64_t rl64(uint64_t v, uint32_t l) {
    uint32_t lo = rl32((uint32_t)v, l);
    uint32_t hi = rl32((uint32_t)(v >> 32), l);
    return ((uint64_t)hi << 32) | lo;
}

// label of node p (p < 64*NW): lab_g lane (p&63), g = p>>6
template<int NW>
__device__ __forceinline__ uint32_t pick_lab(uint32_t lab0, uint32_t lab1,
                                             uint32_t lab2, uint32_t lab3,
                                             uint32_t p) {
    const uint32_t ls = p & 63u;
    uint32_t a = rl32(lab0, ls);
    if (NW == 1) return a;
    uint32_t b = rl32(lab1, ls);
    const uint32_t g = (p >> 6) & 3u;
    if (NW == 2) return (g & 1u) ? b : a;
    uint32_t c = rl32(lab2, ls);
    uint32_t d = (NW > 3) ? rl32(lab3, ls) : c;
    uint32_t ab = (g & 1u) ? b : a;
    uint32_t cd = (g & 1u) ? d : c;
    return (g & 2u) ? cd : ab;
}

// Rows 64K..64K+63; neighbors c < 64*(K+1) -> only NW=K+1 words matter.
// Lane L holds row (64K+L)'s words in registers; row fetch = readlane.
//
// FAST-PREFIX optimization (semantics-preserving):
//   fast==true  <=>  all nodes 0..r-1 currently share one label V.
//   Then a NONEMPTY row r (all neighbors in prefix => all label V) simply
//   adopts V with zero merges — exactly what the sequential reference does.
//   An EMPTY row r leaves labels[r]=r, uniform iff V==r (impossible for r>0
//   since label values only propagate from columns < r) -> drop to slow path.
//   Slow path is the verified original; its exit ballots R (computed anyway)
//   give a free prefix-uniformity test to re-enter fast mode.
//   If fast at chunk entry and ALL 64 rows nonempty (one ballot), the whole
//   chunk collapses to lab_K = V.
template<int NW>
__device__ __forceinline__ void scan_chunk(const int K, const int lane,
                                           uint32_t& lab0, uint32_t& lab1,
                                           uint32_t& lab2, uint32_t& lab3,
                                           uint32_t& labw,
                                           const uint64_t* __restrict__ bits,
                                           bool& fast, uint32_t& V) {
    const int base = (K * 64 + lane) * 4;
    uint64_t Wr0 = bits[base + 0];
    uint64_t Wr1 = (NW > 1) ? bits[base + 1] : 0;
    uint64_t Wr2 = (NW > 2) ? bits[base + 2] : 0;
    uint64_t Wr3 = (NW > 3) ? bits[base + 3] : 0;

    // one ballot: bit L = row (64K+L) has at least one ok-neighbor
    const uint64_t rowOr = Wr0 | Wr1 | Wr2 | Wr3;
    const uint64_t nonempty = __ballot(rowOr != 0);

    if (fast && nonempty == ~0ull) {
        // every row adopts V in sequence; prefix stays uniform throughout
        labw = V;
        return;
    }

    for (int rr = 0; rr < 64; ++rr) {
        const bool rowEmpty = ((nonempty >> rr) & 1ull) == 0ull;
        if (fast) {
            if (!rowEmpty) {
                labw = ((uint32_t)lane == (uint32_t)rr) ? V : labw;
                continue;
            }
            // empty row: labels unchanged; uniform iff V == r (r>0: never)
            fast = (V == (uint32_t)(K * 64 + rr));
            continue;
        }
        // ---------------- slow path: verified original semantics ----------
        const uint64_t w0 = rl64(Wr0, (uint32_t)rr);
        const uint64_t w1 = (NW > 1) ? rl64(Wr1, (uint32_t)rr) : 0;
        const uint64_t w2 = (NW > 2) ? rl64(Wr2, (uint32_t)rr) : 0;
        const uint64_t w3 = (NW > 3) ? rl64(Wr3, (uint32_t)rr) : 0;
        // branchless min set-bit over the row (512 = none)
        uint32_t f0 = w0 ? (uint32_t)__builtin_ctzll(w0) : 512u;
        uint32_t p = f0;
        if (NW > 1) { uint32_t f = w1 ? (uint32_t)__builtin_ctzll(w1) + 64u  : 512u; p = p < f ? p : f; }
        if (NW > 2) { uint32_t f = w2 ? (uint32_t)__builtin_ctzll(w2) + 128u : 512u; p = p < f ? p : f; }
        if (NW > 3) { uint32_t f = w3 ? (uint32_t)__builtin_ctzll(w3) + 192u : 512u; p = p < f ? p : f; }
        const uint32_t lc = pick_lab<NW>(lab0, lab1, lab2, lab3, p & 255u);
        // node r (=64K+rr) adopts lc; empty row -> update lane 64 (no lane)
        const uint32_t upd = (p < 256u) ? (uint32_t)rr : 64u;
        labw = ((uint32_t)lane == upd) ? lc : labw;
        uint32_t cur = lc;
        uint64_t R0, R1 = 0, R2 = 0, R3 = 0;
        for (;;) {
            R0 = __ballot(lab0 != cur);
            if (NW > 1) R1 = __ballot(lab1 != cur);
            if (NW > 2) R2 = __ballot(lab2 != cur);
            if (NW > 3) R3 = __ballot(lab3 != cur);
            const uint64_t Q0 = R0 & w0;
            const uint64_t Q1 = (NW > 1) ? (R1 & w1) : 0;
            const uint64_t Q2 = (NW > 2) ? (R2 & w2) : 0;
            const uint64_t Q3 = (NW > 3) ? (R3 & w3) : 0;
            if (!(Q0 | Q1 | Q2 | Q3)) break;          // common: fall through
            uint32_t h0 = Q0 ? (uint32_t)__builtin_ctzll(Q0) : 512u;
            uint32_t p2 = h0;
            if (NW > 1) { uint32_t h = Q1 ? (uint32_t)__builtin_ctzll(Q1) + 64u  : 512u; p2 = p2 < h ? p2 : h; }
            if (NW > 2) { uint32_t h = Q2 ? (uint32_t)__builtin_ctzll(Q2) + 128u : 512u; p2 = p2 < h ? p2 : h; }
            if (NW > 3) { uint32_t h = Q3 ? (uint32_t)__builtin_ctzll(Q3) + 192u : 512u; p2 = p2 < h ? p2 : h; }
            const uint32_t lc2 = pick_lab<NW>(lab0, lab1, lab2, lab3, p2);
            lab0 = (lab0 == cur) ? lc2 : lab0;
            if (NW > 1) lab1 = (lab1 == cur) ? lc2 : lab1;
            if (NW > 2) lab2 = (lab2 == cur) ? lc2 : lab2;
            if (NW > 3) lab3 = (lab3 == cur) ? lc2 : lab3;
            cur = lc2;
        }
        // ---- prefix-uniformity test from the exit ballots (free) ----
        // prefix = nodes 0..64K+rr ; group K masked to bits <= rr
        const uint64_t pmK = (rr == 63) ? ~0ull : ((1ull << (rr + 1)) - 1ull);
        uint64_t nb = R0 & ((NW - 1 == 0) ? pmK : ~0ull);
        if (NW > 1) nb |= R1 & ((NW - 1 == 1) ? pmK : ~0ull);
        if (NW > 2) nb |= R2 & ((NW - 1 == 2) ? pmK : ~0ull);
        if (NW > 3) nb |= R3 & pmK;
        if (nb == 0) { fast = true; V = cur; }
    }
}

// ---------------------------------------------------------------------------
// Kernel 2. Block 0: build ok-bit matrix in LDS (all 4 waves), wave 0 runs
// the scan (now with fast-prefix shortcut), ranks with 256 threads.
// Blocks >=1: out2 broadcast.
// Bit layout: bits[r*4+g] bit q  <=>  ok(r, 64g+q); lab_g lane L = node 64g+L.
// ---------------------------------------------------------------------------
__global__ __launch_bounds__(256) void k2_scan_out2(float* __restrict__ out) {
    const int tid = threadIdx.x;
    const float* __restrict__ dm = out + OUT2_OFF;

    if (blockIdx.x == 0) {
        __shared__ __align__(16) uint64_t bits[1024];
        __shared__ uint32_t lab_arr[256];
        __shared__ uint32_t pres[256];
        __shared__ uint32_t rnk[256];

        // ---- build ok-bit words with all 256 threads ----
        for (int i = 0; i < 4; ++i) {
            const int wid = i * 256 + tid;     // 0..1023
            const int r = wid >> 2;
            const int gw = wid & 3;
            uint64_t bm = 0;
            const int cbase = gw * 64;
            if (cbase < r) {
                const float4* p = reinterpret_cast<const float4*>(dm + r * 256 + cbase);
                #pragma unroll
                for (int q = 0; q < 16; ++q) {
                    const float4 v = p[q];
                    const int c0 = cbase + q * 4;
                    if (c0 + 0 < r && v.x <= TH_F) bm |= 1ull << (q * 4 + 0);
                    if (c0 + 1 < r && v.y <= TH_F) bm |= 1ull << (q * 4 + 1);
                    if (c0 + 2 < r && v.z <= TH_F) bm |= 1ull << (q * 4 + 2);
                    if (c0 + 3 < r && v.w <= TH_F) bm |= 1ull << (q * 4 + 3);
                }
            }
            bits[wid] = bm;
        }
        __syncthreads();

        // ---- serial scan: wave 0 only ----
        if (tid < 64) {
            const int lane = tid;
            uint32_t lab0 = (uint32_t)lane;
            uint32_t lab1 = (uint32_t)(64 + lane);
            uint32_t lab2 = (uint32_t)(128 + lane);
            uint32_t lab3 = (uint32_t)(192 + lane);
            bool fast = true;        // prefix {} / {0} uniform with V=0
            uint32_t V = 0;

            scan_chunk<1>(0, lane, lab0, lab1, lab2, lab3, lab0, bits, fast, V);
            scan_chunk<2>(1, lane, lab0, lab1, lab2, lab3, lab1, bits, fast, V);
            scan_chunk<3>(2, lane, lab0, lab1, lab2, lab3, lab2, bits, fast, V);
            scan_chunk<4>(3, lane, lab0, lab1, lab2, lab3, lab3, bits, fast, V);

            lab_arr[lane]       = lab0;
            lab_arr[64 + lane]  = lab1;
            lab_arr[128 + lane] = lab2;
            lab_arr[192 + lane] = lab3;
        }
        __syncthreads();

        // ---- ranks: present / cumsum / gather, exactly as reference ----
        pres[tid] = 0;
        __syncthreads();
        pres[lab_arr[tid]] = 1;
        __syncthreads();
        if (tid < 64) {
            const int lane = tid;
            const int c0 = 4 * lane;
            const uint32_t t0 = pres[c0 + 0];
            const uint32_t t1 = pres[c0 + 1];
            const uint32_t t2 = pres[c0 + 2];
            const uint32_t t3 = pres[c0 + 3];
            const uint32_t s0 = t0, s1 = s0 + t1, s2 = s1 + t2, s3 = s2 + t3;
            uint32_t incl = s3;
            #pragma unroll
            for (int off = 1; off < 64; off <<= 1) {
                uint32_t u = __shfl_up(incl, off);
                if (lane >= off) incl += u;
            }
            const uint32_t excl = incl - s3;
            rnk[c0 + 0] = excl + s0 - 1;
            rnk[c0 + 1] = excl + s1 - 1;
            rnk[c0 + 2] = excl + s2 - 1;
            rnk[c0 + 3] = excl + s3 - 1;
        }
        __syncthreads();
        out[OUT1_OFF + tid] = (float)rnk[lab_arr[tid]];
    } else {
        // ---- out2[t] = dm for t = 1..127 (t=0 already holds dm) ----
        const int j = (int)(blockIdx.x - 1) * F4_PER_BLK + tid;
        const vfloat4* __restrict__ dm4 = reinterpret_cast<const vfloat4*>(dm);
        vfloat4* __restrict__ o2 = reinterpret_cast<vfloat4*>(out + OUT2_OFF);
        #pragma unroll
        for (int q = 0; q < 4; ++q) {
            const int jj = j + q * 256;
            __builtin_nontemporal_store(dm4[jj & (NSLICE_F4 - 1)],
                                        o2 + (jj + NSLICE_F4));
        }
    }
}

extern "C" void kernel_launch(void* const* d_in, const int* in_sizes, int n_in,
                              void* d_out, int out_size, void* d_ws, size_t ws_size,
                              hipStream_t stream) {
    const float* v_rel = (const float*)d_in[0];
    const float* w1    = (const float*)d_in[1];
    const float* b1    = (const float*)d_in[2];
    const float* bn_g  = (const float*)d_in[3];
    const float* bn_b  = (const float*)d_in[4];
    const float* bn_m  = (const float*)d_in[5];
    const float* bn_v  = (const float*)d_in[6];
    const float* w2    = (const float*)d_in[7];
    const float* b2    = (const float*)d_in[8];
    float* out = (float*)d_out;

    // K1: dm -> out2 t=0 slice (blocks 0..255) || out0 = v_rel copy
    k1_dm_out0<<<NN + COPY0_BLKS, 256, 0, stream>>>(v_rel, w1, b1, bn_g, bn_b,
                                                    bn_m, bn_v, w2, b2, out);
    // K2: block 0 group scan (fast-prefix) || out2 broadcast
    k2_scan_out2<<<1 + COPY2_BLKS, 256, 0, stream>>>(out);
}